// Round 2
// baseline (615.579 us; speedup 1.0000x reference)
//
#include <hip/hip_runtime.h>
#include <stdint.h>

#define DIM_C   2048
#define INNER_C 8192
#define ROWS    8192      // B*L = 4*2048
#define BM 256
#define BN 256
#define BK 64

using bf16x8 = __attribute__((ext_vector_type(8))) __bf16;
using f32x4  = __attribute__((ext_vector_type(4))) float;
using u16x8  = __attribute__((ext_vector_type(8))) unsigned short;

__device__ __forceinline__ unsigned short f2bf(float f) {
  union { float f; unsigned int u; } v; v.f = f;
  unsigned int u = v.u;
  return (unsigned short)((u + 0x7FFFu + ((u >> 16) & 1u)) >> 16);  // RTNE
}

__device__ __forceinline__ void gld_lds16(const void* g, void* l) {
  __builtin_amdgcn_global_load_lds(
      (__attribute__((address_space(1))) void*)(g),
      (__attribute__((address_space(3))) void*)(l), 16, 0, 0);
}

// --- softmax + per-batch truncation width --------------------------------
__global__ void prep_kernel(const float* __restrict__ logits,
                            float* __restrict__ p_out,
                            int* __restrict__ kb) {
  const int b = threadIdx.x;
  if (b < 4) {
    float x0 = logits[b * 4 + 0], x1 = logits[b * 4 + 1];
    float x2 = logits[b * 4 + 2], x3 = logits[b * 4 + 3];
    float m = fmaxf(fmaxf(x0, x1), fmaxf(x2, x3));
    float e0 = __expf(x0 - m), e1 = __expf(x1 - m);
    float e2 = __expf(x2 - m), e3 = __expf(x3 - m);
    float inv = 1.f / (e0 + e1 + e2 + e3);
    p_out[b * 4 + 0] = e0 * inv;
    p_out[b * 4 + 1] = e1 * inv;
    p_out[b * 4 + 2] = e2 * inv;
    p_out[b * 4 + 3] = e3 * inv;
    int idx = 0; float best = x0;                 // first-max, like jnp.argmax
    if (x1 > best) { best = x1; idx = 1; }
    if (x2 > best) { best = x2; idx = 2; }
    if (x3 > best) { best = x3; idx = 3; }
    kb[b] = (idx + 1) * (INNER_C / 4);
  }
}

// --- fp32 -> bf16 bulk convert (8 elems/thread, 16B stores) --------------
__global__ void cvt_kernel(const float* __restrict__ in,
                           unsigned short* __restrict__ out, int n8) {
  int i = blockIdx.x * blockDim.x + threadIdx.x;
  if (i >= n8) return;
  const float4* p = reinterpret_cast<const float4*>(in) + (size_t)i * 2;
  float4 a = p[0], b = p[1];
  u16x8 r;
  r[0] = f2bf(a.x); r[1] = f2bf(a.y); r[2] = f2bf(a.z); r[3] = f2bf(a.w);
  r[4] = f2bf(b.x); r[5] = f2bf(b.y); r[6] = f2bf(b.z); r[7] = f2bf(b.w);
  *(reinterpret_cast<u16x8*>(out) + i) = r;
}

// --- NT bf16 GEMM, 256x256 tile, BK=64, 8 waves, 2-phase/K-tile pipeline --
// LDS per buffer/matrix: [2 kh][256 rows][32 k] bf16 (row stride 64B ->
// conflict-free b128 frag reads). Double-buffered: 128 KiB total.
// Staging unit "pair" p = (tile p>>1, kh p&1): 4 gld_lds (A:2, B:2).
// Lead = 3 pairs; one s_waitcnt vmcnt(4) per K-tile (pair-granular pipeline).
// MODE 0: C = gelu(A*B^T + bias) -> bf16 H, skip col tiles >= kb[batch]
// MODE 1: C = A*B^T + bias -> f32 out, K-loop truncated to kb[batch]
template <int MODE>
__global__ __launch_bounds__(512, 2) void gemm_bt(
    const unsigned short* __restrict__ A,
    const unsigned short* __restrict__ Bp,
    const float* __restrict__ bias,
    void* __restrict__ Cp,
    const int* __restrict__ kb_arr) {
  constexpr int KDIM = (MODE == 0) ? DIM_C : INNER_C;   // A/B row stride
  constexpr int NTN  = (MODE == 0) ? (INNER_C / BN) : (DIM_C / BN);
  __shared__ __align__(16) unsigned short sm[65536];    // 128 KiB

  // T1: bijective XCD swizzle (nwg % 8 == 0 for both grids)
  const int nwg = gridDim.x;
  const int bid = blockIdx.x;
  const int swz = (bid & 7) * (nwg >> 3) + (bid >> 3);
  const int nt = swz % NTN;
  const int mt = swz / NTN;
  const size_t row0 = (size_t)mt * BM;
  const size_t col0 = (size_t)nt * BN;
  const int batch = (int)(row0 >> 11);                  // 2048 rows / batch
  const int kbv = kb_arr[batch];
  if (MODE == 0 && (int)col0 >= kbv) return;            // masked cols: skip
  const int kTiles = (MODE == 0) ? (DIM_C / BK) : (kbv / BK);  // even (>=32)

  const int tid  = threadIdx.x;
  const int wave = tid >> 6;
  const int lane = tid & 63;
  const int wm = wave >> 2, wn = wave & 3;              // 2x4 wave grid
  const int la = lane & 15, lb4 = lane >> 4;

  // staging: per pair, each wave loads 2x A-chunks + 2x B-chunks of
  // 16 rows x 32 k (1 KiB); lane -> (row lane>>2, k (lane&3)*8)
  const unsigned short* gA0 =
      A + (row0 + (size_t)(wave * 16 + (lane >> 2))) * KDIM + (lane & 3) * 8;
  const unsigned short* gA1 = gA0 + (size_t)128 * KDIM;
  const unsigned short* gB0 =
      Bp + (col0 + (size_t)(wave * 16 + (lane >> 2))) * KDIM + (lane & 3) * 8;
  const unsigned short* gB1 = gB0 + (size_t)128 * KDIM;

  // ds_read fragment offsets (ushort units); row stride 32 ushorts = 64 B
  const int ardo = (wm * 128 + la) * 32 + lb4 * 8;
  const int brdo = 32768 + (wn * 64 + la) * 32 + lb4 * 8;

  f32x4 acc[8][4];
#pragma unroll
  for (int m = 0; m < 8; ++m)
#pragma unroll
    for (int n = 0; n < 4; ++n) acc[m][n] = (f32x4){0.f, 0.f, 0.f, 0.f};

  // prologue: stage pairs 0,1,2; wait pairs 0,1 (allow pair 2 in flight)
#pragma unroll
  for (int q = 0; q < 3; ++q) {
    const int lb = q * 8192, ko = q * 32;
    gld_lds16(gA0 + ko, &sm[lb + wave * 512]);
    gld_lds16(gA1 + ko, &sm[lb + 4096 + wave * 512]);
    gld_lds16(gB0 + ko, &sm[32768 + lb + wave * 512]);
    gld_lds16(gB1 + ko, &sm[32768 + lb + 4096 + wave * 512]);
  }
  asm volatile("s_waitcnt vmcnt(4)" ::: "memory");
  __builtin_amdgcn_s_barrier();

  int pe = 3;                         // next pair to stage (clamped at tail)
  const int pmax = 2 * kTiles - 1;

#define PHASE(BUF, KH)                                                        \
  {                                                                           \
    bf16x8 af[8], bfr[4];                                                     \
    const int ab = (BUF) * 16384 + (KH) * 8192 + ardo;                        \
    const int bb = (BUF) * 16384 + (KH) * 8192 + brdo;                        \
    _Pragma("unroll") for (int m_ = 0; m_ < 8; ++m_)                          \
        af[m_] = *reinterpret_cast<const bf16x8*>(&sm[ab + m_ * 512]);        \
    _Pragma("unroll") for (int n_ = 0; n_ < 4; ++n_)                          \
        bfr[n_] = *reinterpret_cast<const bf16x8*>(&sm[bb + n_ * 512]);       \
    const int lb_ = (pe & 3) * 8192;                                          \
    const int ko_ = pe * 32;                                                  \
    gld_lds16(gA0 + ko_, &sm[lb_ + wave * 512]);                              \
    gld_lds16(gA1 + ko_, &sm[lb_ + 4096 + wave * 512]);                       \
    gld_lds16(gB0 + ko_, &sm[32768 + lb_ + wave * 512]);                      \
    gld_lds16(gB1 + ko_, &sm[32768 + lb_ + 4096 + wave * 512]);               \
    pe = (pe < pmax) ? (pe + 1) : pmax;                                       \
    __builtin_amdgcn_sched_barrier(0);                                        \
    __builtin_amdgcn_s_barrier();                                             \
    asm volatile("s_waitcnt lgkmcnt(0)" ::: "memory");                        \
    __builtin_amdgcn_sched_barrier(0);                                        \
    __builtin_amdgcn_s_setprio(1);                                            \
    _Pragma("unroll") for (int m_ = 0; m_ < 8; ++m_)                          \
        _Pragma("unroll") for (int n_ = 0; n_ < 4; ++n_)                      \
            acc[m_][n_] = __builtin_amdgcn_mfma_f32_16x16x32_bf16(            \
                af[m_], bfr[n_], acc[m_][n_], 0, 0, 0);                       \
    __builtin_amdgcn_s_setprio(0);                                            \
  }

  for (int t = 0; t < kTiles; t += 2) {
    PHASE(0, 0);
    __builtin_amdgcn_sched_barrier(0);
    __builtin_amdgcn_s_barrier();
    PHASE(0, 1);
    asm volatile("s_waitcnt vmcnt(4)" ::: "memory");
    __builtin_amdgcn_s_barrier();
    __builtin_amdgcn_sched_barrier(0);
    PHASE(1, 0);
    __builtin_amdgcn_sched_barrier(0);
    __builtin_amdgcn_s_barrier();
    PHASE(1, 1);
    asm volatile("s_waitcnt vmcnt(4)" ::: "memory");
    __builtin_amdgcn_s_barrier();
    __builtin_amdgcn_sched_barrier(0);
  }
#undef PHASE
  asm volatile("s_waitcnt vmcnt(0)" ::: "memory");  // drain tail DMA writes

  // epilogue: C/D layout col = lane&15, row = (lane>>4)*4 + j  [m89/m91]
#pragma unroll
  for (int m = 0; m < 8; ++m) {
    const size_t rb = row0 + wm * 128 + m * 16 + lb4 * 4;
#pragma unroll
    for (int n = 0; n < 4; ++n) {
      const size_t c = col0 + wn * 64 + n * 16 + la;
      const float bv = bias[c];
#pragma unroll
      for (int j = 0; j < 4; ++j) {
        float x = acc[m][n][j] + bv;
        if (MODE == 0) {
          float g = x / (1.f + __expf(-1.702f * x));  // x*sigmoid(1.702x)
          ((unsigned short*)Cp)[(rb + j) * (size_t)INNER_C + c] = f2bf(g);
        } else {
          ((float*)Cp)[(rb + j) * (size_t)DIM_C + c] = x;
        }
      }
    }
  }
}

extern "C" void kernel_launch(void* const* d_in, const int* in_sizes, int n_in,
                              void* d_out, int out_size, void* d_ws,
                              size_t ws_size, hipStream_t stream) {
  const float* hidden = (const float*)d_in[0];  // [4,2048,2048]
  const float* logitw = (const float*)d_in[1];  // [4,4]
  const float* W1     = (const float*)d_in[2];  // [8192,2048]
  const float* b1     = (const float*)d_in[3];  // [8192]
  const float* W2     = (const float*)d_in[4];  // [2048,8192]
  const float* b2     = (const float*)d_in[5];  // [2048]
  float* out   = (float*)d_out;
  float* p_out = out + (size_t)ROWS * DIM_C;    // tuple tail: p_soft [4,4]

  char* ws = (char*)d_ws;
  int*            kb   = (int*)ws;                                    // 16 B
  unsigned short* Abf  = (unsigned short*)(ws + 256);                 // 32 MiB
  unsigned short* W1bf = (unsigned short*)(ws + 256 + 33554432);      // 32 MiB
  unsigned short* W2bf = (unsigned short*)(ws + 256 + 2 * 33554432);  // 32 MiB
  unsigned short* Hbf  = (unsigned short*)(ws + 256 + 3 * 33554432);  // 128 MiB

  prep_kernel<<<1, 64, 0, stream>>>(logitw, p_out, kb);

  const int n8 = 16777216 / 8;  // each of A/W1/W2 is 16.7M fp32
  cvt_kernel<<<n8 / 256, 256, 0, stream>>>(hidden, Abf, n8);
  cvt_kernel<<<n8 / 256, 256, 0, stream>>>(W1, W1bf, n8);
  cvt_kernel<<<n8 / 256, 256, 0, stream>>>(W2, W2bf, n8);

  gemm_bt<0><<<dim3((INNER_C / BN) * (ROWS / BM)), 512, 0, stream>>>(
      Abf, W1bf, b1, Hbf, kb);
  gemm_bt<1><<<dim3((DIM_C / BN) * (ROWS / BM)), 512, 0, stream>>>(
      Hbf, W2bf, b2, out, kb);
}

// Round 3
// 550.666 us; speedup vs baseline: 1.1179x; 1.1179x over previous
//
#include <hip/hip_runtime.h>
#include <stdint.h>

#define DIM_C   2048
#define INNER_C 8192
#define ROWS    8192      // B*L = 4*2048
#define BM 256
#define BN 256
#define BK 64

using bf16x8 = __attribute__((ext_vector_type(8))) __bf16;
using f32x4  = __attribute__((ext_vector_type(4))) float;
using u16x8  = __attribute__((ext_vector_type(8))) unsigned short;

__device__ __forceinline__ unsigned short f2bf(float f) {
  union { float f; unsigned int u; } v; v.f = f;
  unsigned int u = v.u;
  return (unsigned short)((u + 0x7FFFu + ((u >> 16) & 1u)) >> 16);  // RTNE
}

__device__ __forceinline__ void gld_lds16(const void* g, void* l) {
  __builtin_amdgcn_global_load_lds(
      (__attribute__((address_space(1))) void*)(g),
      (__attribute__((address_space(3))) void*)(l), 16, 0, 0);
}

// --- softmax + per-batch truncation width --------------------------------
__global__ void prep_kernel(const float* __restrict__ logits,
                            float* __restrict__ p_out,
                            int* __restrict__ kb) {
  const int b = threadIdx.x;
  if (b < 4) {
    float x0 = logits[b * 4 + 0], x1 = logits[b * 4 + 1];
    float x2 = logits[b * 4 + 2], x3 = logits[b * 4 + 3];
    float m = fmaxf(fmaxf(x0, x1), fmaxf(x2, x3));
    float e0 = __expf(x0 - m), e1 = __expf(x1 - m);
    float e2 = __expf(x2 - m), e3 = __expf(x3 - m);
    float inv = 1.f / (e0 + e1 + e2 + e3);
    p_out[b * 4 + 0] = e0 * inv;
    p_out[b * 4 + 1] = e1 * inv;
    p_out[b * 4 + 2] = e2 * inv;
    p_out[b * 4 + 3] = e3 * inv;
    int idx = 0; float best = x0;                 // first-max, like jnp.argmax
    if (x1 > best) { best = x1; idx = 1; }
    if (x2 > best) { best = x2; idx = 2; }
    if (x3 > best) { best = x3; idx = 3; }
    kb[b] = (idx + 1) * (INNER_C / 4);
  }
}

// --- fp32 -> bf16 bulk convert (8 elems/thread, 16B stores) --------------
__global__ void cvt_kernel(const float* __restrict__ in,
                           unsigned short* __restrict__ out, int n8) {
  int i = blockIdx.x * blockDim.x + threadIdx.x;
  if (i >= n8) return;
  const float4* p = reinterpret_cast<const float4*>(in) + (size_t)i * 2;
  float4 a = p[0], b = p[1];
  u16x8 r;
  r[0] = f2bf(a.x); r[1] = f2bf(a.y); r[2] = f2bf(a.z); r[3] = f2bf(a.w);
  r[4] = f2bf(b.x); r[5] = f2bf(b.y); r[6] = f2bf(b.z); r[7] = f2bf(b.w);
  *(reinterpret_cast<u16x8*>(out) + i) = r;
}

// --- NT bf16 GEMM, 256x256, BK=64, 8 waves, 4-phase/K-tile (m201 port) ---
// LDS per (buf, mat): [kh 2][256 rows][32 k] ushort (row stride 64B ->
// bank-uniform b128 reads). 2 bufs: 128 KiB.
// Half-tile stage = (mat, rowhalf) x BK = 2 gld_lds/thread (one per kh).
// Phase p of tile t: quadrant MFMA (16) + operand-half ds_reads + 1 stage:
//   P1: read A-lo,B-lo (12), stage (t+1,A1);  MFMA m0-3 x n0-1
//   P2: read B-hi (4),       stage (t+1,B1);  MFMA m0-3 x n2-3
//   P3: read A-hi (8),       stage (t+2,B0);  MFMA m4-7 x n2-3
//   P4:                      stage (t+2,A0);  vmcnt(4); MFMA m4-7 x n0-1
// Region safety: same-parity (t+2) B writes allowed >= P3 (B-hi reads end
// P2), A writes >= P4 (A-hi reads end P3). vmcnt(4) = 2 half-tiles in
// flight guarantees tile t+1 landed before its P1.
// MODE 0: C = gelu(A*B^T + bias) -> bf16 H, skip col tiles >= kb[batch]
// MODE 1: C = A*B^T + bias -> f32 out, K-loop truncated to kb[batch]
template <int MODE>
__global__ __launch_bounds__(512, 2) void gemm_bt(
    const unsigned short* __restrict__ A,
    const unsigned short* __restrict__ Bp,
    const float* __restrict__ bias,
    void* __restrict__ Cp,
    const int* __restrict__ kb_arr) {
  constexpr int KDIM = (MODE == 0) ? DIM_C : INNER_C;   // A/B row stride
  constexpr int NTN  = (MODE == 0) ? (INNER_C / BN) : (DIM_C / BN);
  __shared__ __align__(16) unsigned short sm[65536];    // 128 KiB

  // T1: bijective XCD swizzle (nwg % 8 == 0 for both grids)
  const int nwg = gridDim.x;
  const int bid = blockIdx.x;
  const int swz = (bid & 7) * (nwg >> 3) + (bid >> 3);
  const int nt = swz % NTN;
  const int mt = swz / NTN;
  const size_t row0 = (size_t)mt * BM;
  const size_t col0 = (size_t)nt * BN;
  const int batch = (int)(row0 >> 11);                  // 2048 rows / batch
  const int kbv = kb_arr[batch];
  if (MODE == 0 && (int)col0 >= kbv) return;            // masked cols: skip
  const int kTiles = (MODE == 0) ? (DIM_C / BK) : (kbv / BK);  // even, >=32

  const int tid  = threadIdx.x;
  const int wave = tid >> 6;
  const int lane = tid & 63;
  const int wm = wave >> 2, wn = wave & 3;              // 2x4 wave grid
  const int la = lane & 15, lb4 = lane >> 4;

  // staging: thread -> (row wave*16 + lane>>2, k (lane&3)*8)
  const unsigned short* gA =
      A + (row0 + (size_t)(wave * 16 + (lane >> 2))) * KDIM + (lane & 3) * 8;
  const unsigned short* gB =
      Bp + (col0 + (size_t)(wave * 16 + (lane >> 2))) * KDIM + (lane & 3) * 8;

  // STAGE(gp, matofs, BUF, H, T): one half-tile (2 x gld_lds, one per kh)
#define STAGE(gp, matofs, BUF, H, T)                                          \
  {                                                                           \
    const unsigned short* g_ = gp + (size_t)(H) * 128 * KDIM + (T) * 64;      \
    gld_lds16(g_, &sm[(BUF) * 32768 + (matofs) + (H) * 4096 + wave * 512]);   \
    gld_lds16(g_ + 32,                                                        \
              &sm[(BUF) * 32768 + (matofs) + 8192 + (H) * 4096 + wave * 512]);\
  }

  // frag read bases (ushort units); + m*512 (16 rows), + ks*8192, + buf*32768
  const int aro = (wm * 128 + la) * 32 + lb4 * 8;
  const int bro = 16384 + (wn * 64 + la) * 32 + lb4 * 8;

  f32x4 acc[8][4];
#pragma unroll
  for (int m = 0; m < 8; ++m)
#pragma unroll
    for (int n = 0; n < 4; ++n) acc[m][n] = (f32x4){0.f, 0.f, 0.f, 0.f};

  // prologue: tile0 all 4 half-tiles + tile1 {B0, A0}; allow tile1's 4
  // loads to stay in flight.
  STAGE(gB, 16384, 0, 0, 0);
  STAGE(gA, 0,     0, 0, 0);
  STAGE(gA, 0,     0, 1, 0);
  STAGE(gB, 16384, 0, 1, 0);
  STAGE(gB, 16384, 1, 0, 1);
  STAGE(gA, 0,     1, 0, 1);
  asm volatile("s_waitcnt vmcnt(4)" ::: "memory");
  __builtin_amdgcn_s_barrier();

  bf16x8 aflo[4][2], afhi[4][2], bflo[2][2], bfhi[2][2];

#define MFMA_Q(AF, BF, MO, NO)                                                \
  __builtin_amdgcn_s_setprio(1);                                              \
  _Pragma("unroll") for (int m_ = 0; m_ < 4; ++m_)                            \
      _Pragma("unroll") for (int n_ = 0; n_ < 2; ++n_)                        \
          _Pragma("unroll") for (int k_ = 0; k_ < 2; ++k_)                    \
              acc[(MO) + m_][(NO) + n_] =                                     \
                  __builtin_amdgcn_mfma_f32_16x16x32_bf16(                    \
                      AF[m_][k_], BF[n_][k_], acc[(MO) + m_][(NO) + n_],      \
                      0, 0, 0);                                               \
  __builtin_amdgcn_s_setprio(0);

#define TILE(T, BUF)                                                          \
  {                                                                           \
    const bool s1 = (T) + 1 < kTiles, s2 = (T) + 2 < kTiles;                  \
    /* P1 */                                                                  \
    _Pragma("unroll") for (int m_ = 0; m_ < 4; ++m_)                          \
        _Pragma("unroll") for (int k_ = 0; k_ < 2; ++k_)                      \
            aflo[m_][k_] = *reinterpret_cast<const bf16x8*>(                  \
                &sm[(BUF) * 32768 + k_ * 8192 + aro + m_ * 512]);             \
    _Pragma("unroll") for (int n_ = 0; n_ < 2; ++n_)                          \
        _Pragma("unroll") for (int k_ = 0; k_ < 2; ++k_)                      \
            bflo[n_][k_] = *reinterpret_cast<const bf16x8*>(                  \
                &sm[(BUF) * 32768 + k_ * 8192 + bro + n_ * 512]);             \
    if (s1) { STAGE(gA, 0, (BUF) ^ 1, 1, (T) + 1); }                          \
    asm volatile("s_waitcnt lgkmcnt(8)" ::: "memory");                        \
    __builtin_amdgcn_s_barrier();                                             \
    asm volatile("s_waitcnt lgkmcnt(0)" ::: "memory");                        \
    __builtin_amdgcn_sched_barrier(0);                                        \
    MFMA_Q(aflo, bflo, 0, 0)                                                  \
    __builtin_amdgcn_s_barrier();                                             \
    /* P2 */                                                                  \
    _Pragma("unroll") for (int n_ = 0; n_ < 2; ++n_)                          \
        _Pragma("unroll") for (int k_ = 0; k_ < 2; ++k_)                      \
            bfhi[n_][k_] = *reinterpret_cast<const bf16x8*>(                  \
                &sm[(BUF) * 32768 + k_ * 8192 + bro + 1024 + n_ * 512]);      \
    if (s1) { STAGE(gB, 16384, (BUF) ^ 1, 1, (T) + 1); }                      \
    __builtin_amdgcn_s_barrier();                                             \
    asm volatile("s_waitcnt lgkmcnt(0)" ::: "memory");                        \
    __builtin_amdgcn_sched_barrier(0);                                        \
    MFMA_Q(aflo, bfhi, 0, 2)                                                  \
    __builtin_amdgcn_s_barrier();                                             \
    /* P3 */                                                                  \
    _Pragma("unroll") for (int m_ = 0; m_ < 4; ++m_)                          \
        _Pragma("unroll") for (int k_ = 0; k_ < 2; ++k_)                      \
            afhi[m_][k_] = *reinterpret_cast<const bf16x8*>(                  \
                &sm[(BUF) * 32768 + k_ * 8192 + aro + 2048 + m_ * 512]);      \
    if (s2) { STAGE(gB, 16384, BUF, 0, (T) + 2); }                            \
    __builtin_amdgcn_s_barrier();                                             \
    asm volatile("s_waitcnt lgkmcnt(0)" ::: "memory");                        \
    __builtin_amdgcn_sched_barrier(0);                                        \
    MFMA_Q(afhi, bfhi, 4, 2)                                                  \
    __builtin_amdgcn_s_barrier();                                             \
    /* P4 */                                                                  \
    if (s2) {                                                                 \
      STAGE(gA, 0, BUF, 0, (T) + 2);                                          \
      asm volatile("s_waitcnt vmcnt(4)" ::: "memory");                        \
    } else if (s1) {                                                          \
      asm volatile("s_waitcnt vmcnt(0)" ::: "memory");                        \
    }                                                                         \
    __builtin_amdgcn_s_barrier();                                             \
    __builtin_amdgcn_sched_barrier(0);                                        \
    MFMA_Q(afhi, bflo, 4, 0)                                                  \
    __builtin_amdgcn_s_barrier();                                             \
  }

  for (int t = 0; t < kTiles; t += 2) {
    TILE(t, 0);
    TILE(t + 1, 1);
  }
#undef TILE
#undef MFMA_Q
#undef STAGE

  // epilogue: C/D layout col = lane&15, row = (lane>>4)*4 + j  [m89/m91]
#pragma unroll
  for (int m = 0; m < 8; ++m) {
    const size_t rb = row0 + wm * 128 + m * 16 + lb4 * 4;
#pragma unroll
    for (int n = 0; n < 4; ++n) {
      const size_t c = col0 + wn * 64 + n * 16 + la;
      const float bv = bias[c];
#pragma unroll
      for (int j = 0; j < 4; ++j) {
        float x = acc[m][n][j] + bv;
        if (MODE == 0) {
          float g = x / (1.f + __expf(-1.702f * x));  // x*sigmoid(1.702x)
          ((unsigned short*)Cp)[(rb + j) * (size_t)INNER_C + c] = f2bf(g);
        } else {
          ((float*)Cp)[(rb + j) * (size_t)DIM_C + c] = x;
        }
      }
    }
  }
}

extern "C" void kernel_launch(void* const* d_in, const int* in_sizes, int n_in,
                              void* d_out, int out_size, void* d_ws,
                              size_t ws_size, hipStream_t stream) {
  const float* hidden = (const float*)d_in[0];  // [4,2048,2048]
  const float* logitw = (const float*)d_in[1];  // [4,4]
  const float* W1     = (const float*)d_in[2];  // [8192,2048]
  const float* b1     = (const float*)d_in[3];  // [8192]
  const float* W2     = (const float*)d_in[4];  // [2048,8192]
  const float* b2     = (const float*)d_in[5];  // [2048]
  float* out   = (float*)d_out;
  float* p_out = out + (size_t)ROWS * DIM_C;    // tuple tail: p_soft [4,4]

  char* ws = (char*)d_ws;
  int*            kb   = (int*)ws;                                    // 16 B
  unsigned short* Abf  = (unsigned short*)(ws + 256);                 // 32 MiB
  unsigned short* W1bf = (unsigned short*)(ws + 256 + 33554432);      // 32 MiB
  unsigned short* W2bf = (unsigned short*)(ws + 256 + 2 * 33554432);  // 32 MiB
  unsigned short* Hbf  = (unsigned short*)(ws + 256 + 3 * 33554432);  // 128 MiB

  prep_kernel<<<1, 64, 0, stream>>>(logitw, p_out, kb);

  const int n8 = 16777216 / 8;  // each of A/W1/W2 is 16.7M fp32
  cvt_kernel<<<n8 / 256, 256, 0, stream>>>(hidden, Abf, n8);
  cvt_kernel<<<n8 / 256, 256, 0, stream>>>(W1, W1bf, n8);
  cvt_kernel<<<n8 / 256, 256, 0, stream>>>(W2, W2bf, n8);

  gemm_bt<0><<<dim3((INNER_C / BN) * (ROWS / BM)), 512, 0, stream>>>(
      Abf, W1bf, b1, Hbf, kb);
  gemm_bt<1><<<dim3((DIM_C / BN) * (ROWS / BM)), 512, 0, stream>>>(
      Hbf, W2bf, b2, out, kb);
}

// Round 4
// 516.606 us; speedup vs baseline: 1.1916x; 1.0659x over previous
//
#include <hip/hip_runtime.h>
#include <stdint.h>

#define DIM_C   2048
#define INNER_C 8192
#define ROWS    8192      // B*L = 4*2048
#define BM 256
#define BN 256
#define BK 64

using bf16x8 = __attribute__((ext_vector_type(8))) __bf16;
using f32x4  = __attribute__((ext_vector_type(4))) float;
using u16x8  = __attribute__((ext_vector_type(8))) unsigned short;

__device__ __forceinline__ unsigned short f2bf(float f) {
  union { float f; unsigned int u; } v; v.f = f;
  unsigned int u = v.u;
  return (unsigned short)((u + 0x7FFFu + ((u >> 16) & 1u)) >> 16);  // RTNE
}

__device__ __forceinline__ void gld_lds16(const void* g, void* l) {
  __builtin_amdgcn_global_load_lds(
      (__attribute__((address_space(1))) void*)(g),
      (__attribute__((address_space(3))) void*)(l), 16, 0, 0);
}

// --- softmax + per-batch truncation width --------------------------------
__global__ void prep_kernel(const float* __restrict__ logits,
                            float* __restrict__ p_out,
                            int* __restrict__ kb) {
  const int b = threadIdx.x;
  if (b < 4) {
    float x0 = logits[b * 4 + 0], x1 = logits[b * 4 + 1];
    float x2 = logits[b * 4 + 2], x3 = logits[b * 4 + 3];
    float m = fmaxf(fmaxf(x0, x1), fmaxf(x2, x3));
    float e0 = __expf(x0 - m), e1 = __expf(x1 - m);
    float e2 = __expf(x2 - m), e3 = __expf(x3 - m);
    float inv = 1.f / (e0 + e1 + e2 + e3);
    p_out[b * 4 + 0] = e0 * inv;
    p_out[b * 4 + 1] = e1 * inv;
    p_out[b * 4 + 2] = e2 * inv;
    p_out[b * 4 + 3] = e3 * inv;
    int idx = 0; float best = x0;                 // first-max, like jnp.argmax
    if (x1 > best) { best = x1; idx = 1; }
    if (x2 > best) { best = x2; idx = 2; }
    if (x3 > best) { best = x3; idx = 3; }
    kb[b] = (idx + 1) * (INNER_C / 4);
  }
}

// --- fp32 -> bf16 bulk convert (8 elems/thread, 16B stores) --------------
__global__ void cvt_kernel(const float* __restrict__ in,
                           unsigned short* __restrict__ out, int n8) {
  int i = blockIdx.x * blockDim.x + threadIdx.x;
  if (i >= n8) return;
  const float4* p = reinterpret_cast<const float4*>(in) + (size_t)i * 2;
  float4 a = p[0], b = p[1];
  u16x8 r;
  r[0] = f2bf(a.x); r[1] = f2bf(a.y); r[2] = f2bf(a.z); r[3] = f2bf(a.w);
  r[4] = f2bf(b.x); r[5] = f2bf(b.y); r[6] = f2bf(b.z); r[7] = f2bf(b.w);
  *(reinterpret_cast<u16x8*>(out) + i) = r;
}

// --- NT bf16 GEMM, 256x256, BK=64, 8 waves, 4-phase/K-tile ---------------
// LDS per (buf, mat): [kh 2][256 rows][4 slots x 16B] with slot XOR-swizzle
// slot' = slot ^ ((row>>1)&3): bank_quad(la) = 4*(la&1) + (lb4^((la>>1)&3))
// -> all 8 quads covered twice per 16 lanes = conflict-free b128 reads.
// Swizzle applied on BOTH sides (rule 21): pre-swizzled global source in
// STAGE (LDS dest linear for global_load_lds) + swizzled ds_read slot.
// Phase p of tile t: quadrant MFMA (16) + operand-half ds_reads + 1 stage:
//   P1: read A-lo,B-lo (12), stage (t+1,A1);  MFMA m0-3 x n0-1
//   P2: read B-hi (4),       stage (t+1,B1);  MFMA m0-3 x n2-3
//   P3: read A-hi (8),       stage (t+2,B0);  MFMA m4-7 x n2-3
//   P4:                      stage (t+2,A0);  vmcnt(4); MFMA m4-7 x n0-1
// vmcnt(4) FIFO proof: at t's P4, outstanding = {t+1:A1,B1; t+2:B0,A0};
// keep 4 -> t+1 halves landed. At t+1's P4, retire all t+2 halves. Safe.
// MODE 0: C = gelu(A*B^T + bias) -> bf16 H, skip col tiles >= kb[batch]
// MODE 1: C = A*B^T + bias -> f32 out, K-loop truncated to kb[batch]
template <int MODE>
__global__ __launch_bounds__(512, 2) void gemm_bt(
    const unsigned short* __restrict__ A,
    const unsigned short* __restrict__ Bp,
    const float* __restrict__ bias,
    void* __restrict__ Cp,
    const int* __restrict__ kb_arr) {
  constexpr int KDIM = (MODE == 0) ? DIM_C : INNER_C;   // A/B row stride
  constexpr int NTN  = (MODE == 0) ? (INNER_C / BN) : (DIM_C / BN);
  __shared__ __align__(16) unsigned short sm[65536];    // 128 KiB

  // T1: bijective XCD swizzle (nwg % 8 == 0 for both grids)
  const int nwg = gridDim.x;
  const int bid = blockIdx.x;
  const int swz = (bid & 7) * (nwg >> 3) + (bid >> 3);
  const int nt = swz % NTN;
  const int mt = swz / NTN;
  const size_t row0 = (size_t)mt * BM;
  const size_t col0 = (size_t)nt * BN;
  const int batch = (int)(row0 >> 11);                  // 2048 rows / batch
  const int kbv = kb_arr[batch];
  if (MODE == 0 && (int)col0 >= kbv) return;            // masked cols: skip
  const int kTiles = (MODE == 0) ? (DIM_C / BK) : (kbv / BK);  // even, >=32

  const int tid  = threadIdx.x;
  const int wave = tid >> 6;
  const int lane = tid & 63;
  const int wm = wave >> 2, wn = wave & 3;              // 2x4 wave grid
  const int la = lane & 15, lb4 = lane >> 4;

  // staging: thread -> row wave*16 + lane>>2; global slot pre-swizzled so
  // linear LDS dest holds slot' = slot ^ ((row>>1)&3), (row>>1)&3 = (lane>>3)&3
  const int sslot = ((lane & 3) ^ ((lane >> 3) & 3)) * 8;
  const unsigned short* gA =
      A + (row0 + (size_t)(wave * 16 + (lane >> 2))) * KDIM + sslot;
  const unsigned short* gB =
      Bp + (col0 + (size_t)(wave * 16 + (lane >> 2))) * KDIM + sslot;

  // STAGE(gp, matofs, BUF, H, T): one half-tile (2 x gld_lds, one per kh)
#define STAGE(gp, matofs, BUF, H, T)                                          \
  {                                                                           \
    const unsigned short* g_ = gp + (size_t)(H) * 128 * KDIM + (T) * 64;      \
    gld_lds16(g_, &sm[(BUF) * 32768 + (matofs) + (H) * 4096 + wave * 512]);   \
    gld_lds16(g_ + 32,                                                        \
              &sm[(BUF) * 32768 + (matofs) + 8192 + (H) * 4096 + wave * 512]);\
  }

  // frag read bases (ushort units); row stride 32, swizzled 8-ushort slot.
  // (row>>1)&3 == (la>>1)&3 since all other row terms are multiples of 8.
  const int rslot = (lb4 ^ ((la >> 1) & 3)) * 8;
  const int aro = (wm * 128 + la) * 32 + rslot;
  const int bro = 16384 + (wn * 64 + la) * 32 + rslot;

  f32x4 acc[8][4];
#pragma unroll
  for (int m = 0; m < 8; ++m)
#pragma unroll
    for (int n = 0; n < 4; ++n) acc[m][n] = (f32x4){0.f, 0.f, 0.f, 0.f};

  // prologue: tile0 all 4 half-tiles + tile1 {B0, A0}; allow tile1's 4
  // loads to stay in flight.
  STAGE(gB, 16384, 0, 0, 0);
  STAGE(gA, 0,     0, 0, 0);
  STAGE(gA, 0,     0, 1, 0);
  STAGE(gB, 16384, 0, 1, 0);
  STAGE(gB, 16384, 1, 0, 1);
  STAGE(gA, 0,     1, 0, 1);
  asm volatile("s_waitcnt vmcnt(4)" ::: "memory");
  __builtin_amdgcn_s_barrier();

  bf16x8 aflo[4][2], afhi[4][2], bflo[2][2], bfhi[2][2];

#define MFMA_Q(AF, BF, MO, NO)                                                \
  __builtin_amdgcn_s_setprio(1);                                              \
  _Pragma("unroll") for (int m_ = 0; m_ < 4; ++m_)                            \
      _Pragma("unroll") for (int n_ = 0; n_ < 2; ++n_)                        \
          _Pragma("unroll") for (int k_ = 0; k_ < 2; ++k_)                    \
              acc[(MO) + m_][(NO) + n_] =                                     \
                  __builtin_amdgcn_mfma_f32_16x16x32_bf16(                    \
                      AF[m_][k_], BF[n_][k_], acc[(MO) + m_][(NO) + n_],      \
                      0, 0, 0);                                               \
  __builtin_amdgcn_s_setprio(0);

#define TILE(T, BUF)                                                          \
  {                                                                           \
    const bool s1 = (T) + 1 < kTiles, s2 = (T) + 2 < kTiles;                  \
    /* P1 */                                                                  \
    _Pragma("unroll") for (int m_ = 0; m_ < 4; ++m_)                          \
        _Pragma("unroll") for (int k_ = 0; k_ < 2; ++k_)                      \
            aflo[m_][k_] = *reinterpret_cast<const bf16x8*>(                  \
                &sm[(BUF) * 32768 + k_ * 8192 + aro + m_ * 512]);             \
    _Pragma("unroll") for (int n_ = 0; n_ < 2; ++n_)                          \
        _Pragma("unroll") for (int k_ = 0; k_ < 2; ++k_)                      \
            bflo[n_][k_] = *reinterpret_cast<const bf16x8*>(                  \
                &sm[(BUF) * 32768 + k_ * 8192 + bro + n_ * 512]);             \
    if (s1) { STAGE(gA, 0, (BUF) ^ 1, 1, (T) + 1); }                          \
    asm volatile("s_waitcnt lgkmcnt(8)" ::: "memory");                        \
    __builtin_amdgcn_s_barrier();                                             \
    asm volatile("s_waitcnt lgkmcnt(0)" ::: "memory");                        \
    __builtin_amdgcn_sched_barrier(0);                                        \
    MFMA_Q(aflo, bflo, 0, 0)                                                  \
    __builtin_amdgcn_s_barrier();                                             \
    /* P2 */                                                                  \
    _Pragma("unroll") for (int n_ = 0; n_ < 2; ++n_)                          \
        _Pragma("unroll") for (int k_ = 0; k_ < 2; ++k_)                      \
            bfhi[n_][k_] = *reinterpret_cast<const bf16x8*>(                  \
                &sm[(BUF) * 32768 + k_ * 8192 + bro + 1024 + n_ * 512]);      \
    if (s1) { STAGE(gB, 16384, (BUF) ^ 1, 1, (T) + 1); }                      \
    __builtin_amdgcn_s_barrier();                                             \
    asm volatile("s_waitcnt lgkmcnt(0)" ::: "memory");                        \
    __builtin_amdgcn_sched_barrier(0);                                        \
    MFMA_Q(aflo, bfhi, 0, 2)                                                  \
    __builtin_amdgcn_s_barrier();                                             \
    /* P3 */                                                                  \
    _Pragma("unroll") for (int m_ = 0; m_ < 4; ++m_)                          \
        _Pragma("unroll") for (int k_ = 0; k_ < 2; ++k_)                      \
            afhi[m_][k_] = *reinterpret_cast<const bf16x8*>(                  \
                &sm[(BUF) * 32768 + k_ * 8192 + aro + 2048 + m_ * 512]);      \
    if (s2) { STAGE(gB, 16384, BUF, 0, (T) + 2); }                            \
    __builtin_amdgcn_s_barrier();                                             \
    asm volatile("s_waitcnt lgkmcnt(0)" ::: "memory");                        \
    __builtin_amdgcn_sched_barrier(0);                                        \
    MFMA_Q(afhi, bfhi, 4, 2)                                                  \
    __builtin_amdgcn_s_barrier();                                             \
    /* P4 */                                                                  \
    if (s2) {                                                                 \
      STAGE(gA, 0, BUF, 0, (T) + 2);                                          \
      asm volatile("s_waitcnt vmcnt(4)" ::: "memory");                        \
    } else if (s1) {                                                          \
      asm volatile("s_waitcnt vmcnt(0)" ::: "memory");                        \
    }                                                                         \
    __builtin_amdgcn_s_barrier();                                             \
    __builtin_amdgcn_sched_barrier(0);                                        \
    MFMA_Q(afhi, bflo, 4, 0)                                                  \
    __builtin_amdgcn_s_barrier();                                             \
  }

  for (int t = 0; t < kTiles; t += 2) {
    TILE(t, 0);
    TILE(t + 1, 1);
  }
#undef TILE
#undef MFMA_Q
#undef STAGE

  // epilogue: C/D layout col = lane&15, row = (lane>>4)*4 + j  [m89/m91]
#pragma unroll
  for (int m = 0; m < 8; ++m) {
    const size_t rb = row0 + wm * 128 + m * 16 + lb4 * 4;
#pragma unroll
    for (int n = 0; n < 4; ++n) {
      const size_t c = col0 + wn * 64 + n * 16 + la;
      const float bv = bias[c];
#pragma unroll
      for (int j = 0; j < 4; ++j) {
        float x = acc[m][n][j] + bv;
        if (MODE == 0) {
          float g = x / (1.f + __expf(-1.702f * x));  // x*sigmoid(1.702x)
          ((unsigned short*)Cp)[(rb + j) * (size_t)INNER_C + c] = f2bf(g);
        } else {
          ((float*)Cp)[(rb + j) * (size_t)DIM_C + c] = x;
        }
      }
    }
  }
}

extern "C" void kernel_launch(void* const* d_in, const int* in_sizes, int n_in,
                              void* d_out, int out_size, void* d_ws,
                              size_t ws_size, hipStream_t stream) {
  const float* hidden = (const float*)d_in[0];  // [4,2048,2048]
  const float* logitw = (const float*)d_in[1];  // [4,4]
  const float* W1     = (const float*)d_in[2];  // [8192,2048]
  const float* b1     = (const float*)d_in[3];  // [8192]
  const float* W2     = (const float*)d_in[4];  // [2048,8192]
  const float* b2     = (const float*)d_in[5];  // [2048]
  float* out   = (float*)d_out;
  float* p_out = out + (size_t)ROWS * DIM_C;    // tuple tail: p_soft [4,4]

  char* ws = (char*)d_ws;
  int*            kb   = (int*)ws;                                    // 16 B
  unsigned short* Abf  = (unsigned short*)(ws + 256);                 // 32 MiB
  unsigned short* W1bf = (unsigned short*)(ws + 256 + 33554432);      // 32 MiB
  unsigned short* W2bf = (unsigned short*)(ws + 256 + 2 * 33554432);  // 32 MiB
  unsigned short* Hbf  = (unsigned short*)(ws + 256 + 3 * 33554432);  // 128 MiB

  prep_kernel<<<1, 64, 0, stream>>>(logitw, p_out, kb);

  const int n8 = 16777216 / 8;  // each of A/W1/W2 is 16.7M fp32
  cvt_kernel<<<n8 / 256, 256, 0, stream>>>(hidden, Abf, n8);
  cvt_kernel<<<n8 / 256, 256, 0, stream>>>(W1, W1bf, n8);
  cvt_kernel<<<n8 / 256, 256, 0, stream>>>(W2, W2bf, n8);

  gemm_bt<0><<<dim3((INNER_C / BN) * (ROWS / BM)), 512, 0, stream>>>(
      Abf, W1bf, b1, Hbf, kb);
  gemm_bt<1><<<dim3((DIM_C / BN) * (ROWS / BM)), 512, 0, stream>>>(
      Hbf, W2bf, b2, out, kb);
}

// Round 5
// 506.318 us; speedup vs baseline: 1.2158x; 1.0203x over previous
//
#include <hip/hip_runtime.h>
#include <stdint.h>

#define DIM_C   2048
#define INNER_C 8192
#define ROWS    8192      // B*L = 4*2048
#define BM 256
#define BN 256
#define BK 64

using bf16x8 = __attribute__((ext_vector_type(8))) __bf16;
using f32x4  = __attribute__((ext_vector_type(4))) float;
using u16x8  = __attribute__((ext_vector_type(8))) unsigned short;

__device__ __forceinline__ unsigned short f2bf(float f) {
  union { float f; unsigned int u; } v; v.f = f;
  unsigned int u = v.u;
  return (unsigned short)((u + 0x7FFFu + ((u >> 16) & 1u)) >> 16);  // RTNE
}

__device__ __forceinline__ void gld_lds16(const void* g, void* l) {
  __builtin_amdgcn_global_load_lds(
      (__attribute__((address_space(1))) void*)(g),
      (__attribute__((address_space(3))) void*)(l), 16, 0, 0);
}

// --- softmax + per-batch truncation width --------------------------------
__global__ void prep_kernel(const float* __restrict__ logits,
                            float* __restrict__ p_out,
                            int* __restrict__ kb) {
  const int b = threadIdx.x;
  if (b < 4) {
    float x0 = logits[b * 4 + 0], x1 = logits[b * 4 + 1];
    float x2 = logits[b * 4 + 2], x3 = logits[b * 4 + 3];
    float m = fmaxf(fmaxf(x0, x1), fmaxf(x2, x3));
    float e0 = __expf(x0 - m), e1 = __expf(x1 - m);
    float e2 = __expf(x2 - m), e3 = __expf(x3 - m);
    float inv = 1.f / (e0 + e1 + e2 + e3);
    p_out[b * 4 + 0] = e0 * inv;
    p_out[b * 4 + 1] = e1 * inv;
    p_out[b * 4 + 2] = e2 * inv;
    p_out[b * 4 + 3] = e3 * inv;
    int idx = 0; float best = x0;                 // first-max, like jnp.argmax
    if (x1 > best) { best = x1; idx = 1; }
    if (x2 > best) { best = x2; idx = 2; }
    if (x3 > best) { best = x3; idx = 3; }
    kb[b] = (idx + 1) * (INNER_C / 4);
  }
}

// --- fp32 -> bf16 bulk convert (8 elems/thread, 16B stores) --------------
__global__ void cvt_kernel(const float* __restrict__ in,
                           unsigned short* __restrict__ out, int n8) {
  int i = blockIdx.x * blockDim.x + threadIdx.x;
  if (i >= n8) return;
  const float4* p = reinterpret_cast<const float4*>(in) + (size_t)i * 2;
  float4 a = p[0], b = p[1];
  u16x8 r;
  r[0] = f2bf(a.x); r[1] = f2bf(a.y); r[2] = f2bf(a.z); r[3] = f2bf(a.w);
  r[4] = f2bf(b.x); r[5] = f2bf(b.y); r[6] = f2bf(b.z); r[7] = f2bf(b.w);
  *(reinterpret_cast<u16x8*>(out) + i) = r;
}

// --- NT bf16 GEMM, 256x256, BK=64, 8 waves, 4-phase/K-tile ---------------
// LDS per (buf, mat): [kh 2][256 perm-rows][4 slots x 16B], slot XOR-swizzle
// slot' = slot ^ ((p>>1)&3)  (p = permuted LDS row) -> conflict-free b128.
// Row permutation groups each matrix's fragment read sets into contiguous
// stage halves: A: p = (g>>7)*64 + (g&63) (+128 for g&127>=64)  -> half0 =
// af-lo rows {0-63,128-191}; B: p = (g>>6)*32 + (g&31) (+128)  -> half0 =
// bf-lo rows {wn*64+[0,31]}. Per-wave staged rows stay contiguous in g.
// Phases of tile t (buf = t&1), stages all target buf^1 (quiescent):
//   P1: read af-lo(8)+bf-lo(4); stage (t+1,B-lo); MFMA [0-3][0-1]; vmcnt(4)
//   P2: read bf-hi(4);          stage (t+1,A-lo); MFMA [0-3][2-3]; vmcnt(4)
//   P3: read af-hi(8, overwrites af); stage (t+1,B-hi); MFMA [4-7][2-3]
//   P4:                         stage (t+1,A-hi); MFMA [4-7][0-1]; vmcnt(4)
// vmcnt(4) at end-of-phase (before the barrier all waves cross) retires
// exactly the half needed next phase; stage-to-use distance = 4 phases.
// MODE 0: C = gelu(A*B^T + bias) -> bf16 H, skip col tiles >= kb[batch]
// MODE 1: C = A*B^T + bias -> f32 out, K-loop truncated to kb[batch]
template <int MODE>
__global__ __launch_bounds__(512, 2) void gemm_bt(
    const unsigned short* __restrict__ A,
    const unsigned short* __restrict__ Bp,
    const float* __restrict__ bias,
    void* __restrict__ Cp,
    const int* __restrict__ kb_arr) {
  constexpr int KDIM = (MODE == 0) ? DIM_C : INNER_C;   // A/B row stride
  constexpr int NTN  = (MODE == 0) ? (INNER_C / BN) : (DIM_C / BN);
  __shared__ __align__(16) unsigned short sm[65536];    // 128 KiB

  // T1: bijective XCD swizzle (nwg % 8 == 0 for both grids)
  const int nwg = gridDim.x;
  const int bid = blockIdx.x;
  const int swz = (bid & 7) * (nwg >> 3) + (bid >> 3);
  const int nt = swz % NTN;
  const int mt = swz / NTN;
  const size_t row0 = (size_t)mt * BM;
  const size_t col0 = (size_t)nt * BN;
  const int batch = (int)(row0 >> 11);                  // 2048 rows / batch
  const int kbv = kb_arr[batch];
  if (MODE == 0 && (int)col0 >= kbv) return;            // masked cols: skip
  const int kTiles = (MODE == 0) ? (DIM_C / BK) : (kbv / BK);  // even, >=32

  const int tid  = threadIdx.x;
  const int wave = tid >> 6;
  const int lane = tid & 63;
  const int wm = wave >> 2, wn = wave & 3;              // 2x4 wave grid
  const int la = lane & 15, lb4 = lane >> 4;

  // staging bases (permuted-row order; per-wave 16 contiguous global rows)
  const int sslot = ((lane & 3) ^ ((lane >> 3) & 3)) * 8;
  const unsigned short* gA =
      A + (row0 + (size_t)((wave >> 2) * 128 + (wave & 3) * 16 + (lane >> 2)))
              * KDIM + sslot;
  const unsigned short* gB =
      Bp + (col0 + (size_t)((wave >> 1) * 64 + (wave & 1) * 16 + (lane >> 2)))
               * KDIM + sslot;

  // STAGE: one half-tile (2 x gld_lds, one per kh). HROWS: A=64, B=32.
#define STAGE(gp, matofs, BUF, H, T, HROWS)                                   \
  {                                                                           \
    const unsigned short* g_ = gp + (size_t)(H) * (HROWS) * KDIM + (T) * 64;  \
    gld_lds16(g_, &sm[(BUF) * 32768 + (matofs) + (H) * 4096 + wave * 512]);   \
    gld_lds16(g_ + 32,                                                        \
              &sm[(BUF) * 32768 + (matofs) + 8192 + (H) * 4096 + wave * 512]);\
  }

#define VMW_(N) asm volatile("s_waitcnt vmcnt(" #N ")" ::: "memory")
#define VMW(N) VMW_(N)
#define LGK_(N) asm volatile("s_waitcnt lgkmcnt(" #N ")" ::: "memory")
#define LGK(N) LGK_(N)
#define BAR __builtin_amdgcn_s_barrier()

  // frag read bases (ushort units); permuted row p, stride 32, swz slot.
  const int rslot = (lb4 ^ ((la >> 1) & 3)) * 8;
  const int aro = (wm * 64 + la) * 32 + rslot;          // af-lo p-base
  const int bro = 16384 + (wn * 32 + la) * 32 + rslot;  // bf-lo p-base

  f32x4 acc[8][4];
#pragma unroll
  for (int m = 0; m < 8; ++m)
#pragma unroll
    for (int n = 0; n < 4; ++n) acc[m][n] = (f32x4){0.f, 0.f, 0.f, 0.f};

  bf16x8 af[4][2], bf[2][2], bf2[2][2];

#define RD_AF(BUF, HI)                                                        \
  _Pragma("unroll") for (int m_ = 0; m_ < 4; ++m_)                            \
      _Pragma("unroll") for (int k_ = 0; k_ < 2; ++k_)                        \
          af[m_][k_] = *reinterpret_cast<const bf16x8*>(                      \
              &sm[(BUF) * 32768 + k_ * 8192 + aro + (HI) * 4096 + m_ * 512]);

#define RD_BF(DST, BUF, HI)                                                   \
  _Pragma("unroll") for (int n_ = 0; n_ < 2; ++n_)                            \
      _Pragma("unroll") for (int k_ = 0; k_ < 2; ++k_)                        \
          DST[n_][k_] = *reinterpret_cast<const bf16x8*>(                     \
              &sm[(BUF) * 32768 + k_ * 8192 + bro + (HI) * 4096 + n_ * 512]);

#define MFMA_Q(AF, BF, MO, NO)                                                \
  __builtin_amdgcn_s_setprio(1);                                              \
  _Pragma("unroll") for (int m_ = 0; m_ < 4; ++m_)                            \
      _Pragma("unroll") for (int n_ = 0; n_ < 2; ++n_)                        \
          _Pragma("unroll") for (int k_ = 0; k_ < 2; ++k_)                    \
              acc[(MO) + m_][(NO) + n_] =                                     \
                  __builtin_amdgcn_mfma_f32_16x16x32_bf16(                    \
                      AF[m_][k_], BF[n_][k_], acc[(MO) + m_][(NO) + n_],      \
                      0, 0, 0);                                               \
  __builtin_amdgcn_s_setprio(0);

  // prologue: stage tile0's 4 halves (FIFO: Blo, Alo, Bhi, Ahi)
  STAGE(gB, 16384, 0, 0, 0, 32);
  STAGE(gA, 0,     0, 0, 0, 64);
  STAGE(gB, 16384, 0, 1, 0, 32);
  STAGE(gA, 0,     0, 1, 0, 64);
  VMW(4);                                   // Blo, Alo landed
  BAR;

#define TILE_S(T, BUF)                                                        \
  { /* P1 */                                                                  \
    RD_AF(BUF, 0) RD_BF(bf, BUF, 0)                                           \
    STAGE(gB, 16384, (BUF) ^ 1, 0, (T) + 1, 32);                              \
    LGK(8); BAR; LGK(0);                                                      \
    MFMA_Q(af, bf, 0, 0)                                                      \
    VMW(4); BAR;                                                              \
    /* P2 */                                                                  \
    RD_BF(bf2, BUF, 1)                                                        \
    STAGE(gA, 0, (BUF) ^ 1, 0, (T) + 1, 64);                                  \
    BAR; LGK(0);                                                              \
    MFMA_Q(af, bf2, 0, 2)                                                     \
    VMW(4); BAR;                                                              \
    /* P3 */                                                                  \
    RD_AF(BUF, 1)                                                             \
    STAGE(gB, 16384, (BUF) ^ 1, 1, (T) + 1, 32);                              \
    BAR; LGK(0);                                                              \
    MFMA_Q(af, bf2, 4, 2)                                                     \
    BAR;                                                                      \
    /* P4 */                                                                  \
    STAGE(gA, 0, (BUF) ^ 1, 1, (T) + 1, 64);                                  \
    BAR;                                                                      \
    MFMA_Q(af, bf, 4, 0)                                                      \
    VMW(4); BAR;                                                              \
  }

#define TILE_T(BUF)                                                           \
  { /* P1 */                                                                  \
    RD_AF(BUF, 0) RD_BF(bf, BUF, 0)                                           \
    LGK(8); BAR; LGK(0);                                                      \
    MFMA_Q(af, bf, 0, 0)                                                      \
    VMW(2); BAR;                                                              \
    /* P2 */                                                                  \
    RD_BF(bf2, BUF, 1)                                                        \
    BAR; LGK(0);                                                              \
    MFMA_Q(af, bf2, 0, 2)                                                     \
    VMW(0); BAR;                                                              \
    /* P3 */                                                                  \
    RD_AF(BUF, 1)                                                             \
    BAR; LGK(0);                                                              \
    MFMA_Q(af, bf2, 4, 2)                                                     \
    /* P4 (registers only) */                                                 \
    MFMA_Q(af, bf, 4, 0)                                                      \
  }

  for (int t = 0; t < kTiles - 2; t += 2) {
    TILE_S(t, 0);
    TILE_S(t + 1, 1);
  }
  TILE_S(kTiles - 2, 0);
  TILE_T(1);

#undef TILE_S
#undef TILE_T
#undef MFMA_Q
#undef RD_AF
#undef RD_BF
#undef STAGE

  // epilogue: C/D layout col = lane&15, row = (lane>>4)*4 + j  [m89/m91]
#pragma unroll
  for (int m = 0; m < 8; ++m) {
    const size_t rb = row0 + wm * 128 + m * 16 + lb4 * 4;
#pragma unroll
    for (int n = 0; n < 4; ++n) {
      const size_t c = col0 + wn * 64 + n * 16 + la;
      const float bv = bias[c];
#pragma unroll
      for (int j = 0; j < 4; ++j) {
        float x = acc[m][n][j] + bv;
        if (MODE == 0) {
          float g = x / (1.f + __expf(-1.702f * x));  // x*sigmoid(1.702x)
          ((unsigned short*)Cp)[(rb + j) * (size_t)INNER_C + c] = f2bf(g);
        } else {
          ((float*)Cp)[(rb + j) * (size_t)DIM_C + c] = x;
        }
      }
    }
  }
}

extern "C" void kernel_launch(void* const* d_in, const int* in_sizes, int n_in,
                              void* d_out, int out_size, void* d_ws,
                              size_t ws_size, hipStream_t stream) {
  const float* hidden = (const float*)d_in[0];  // [4,2048,2048]
  const float* logitw = (const float*)d_in[1];  // [4,4]
  const float* W1     = (const float*)d_in[2];  // [8192,2048]
  const float* b1     = (const float*)d_in[3];  // [8192]
  const float* W2     = (const float*)d_in[4];  // [2048,8192]
  const float* b2     = (const float*)d_in[5];  // [2048]
  float* out   = (float*)d_out;
  float* p_out = out + (size_t)ROWS * DIM_C;    // tuple tail: p_soft [4,4]

  char* ws = (char*)d_ws;
  int*            kb   = (int*)ws;                                    // 16 B
  unsigned short* Abf  = (unsigned short*)(ws + 256);                 // 32 MiB
  unsigned short* W1bf = (unsigned short*)(ws + 256 + 33554432);      // 32 MiB
  unsigned short* W2bf = (unsigned short*)(ws + 256 + 2 * 33554432);  // 32 MiB
  unsigned short* Hbf  = (unsigned short*)(ws + 256 + 3 * 33554432);  // 128 MiB

  prep_kernel<<<1, 64, 0, stream>>>(logitw, p_out, kb);

  const int n8 = 16777216 / 8;  // each of A/W1/W2 is 16.7M fp32
  cvt_kernel<<<n8 / 256, 256, 0, stream>>>(hidden, Abf, n8);
  cvt_kernel<<<n8 / 256, 256, 0, stream>>>(W1, W1bf, n8);
  cvt_kernel<<<n8 / 256, 256, 0, stream>>>(W2, W2bf, n8);

  gemm_bt<0><<<dim3((INNER_C / BN) * (ROWS / BM)), 512, 0, stream>>>(
      Abf, W1bf, b1, Hbf, kb);
  gemm_bt<1><<<dim3((DIM_C / BN) * (ROWS / BM)), 512, 0, stream>>>(
      Hbf, W2bf, b2, out, kb);
}